// Round 1
// baseline (135.994 us; speedup 1.0000x reference)
//
#include <hip/hip_runtime.h>
#include <math.h>

#define M 1024

// diag(Q) kernel tiling
#define TI 64          // i-tile (output indices per block)
#define KCH 16         // k sub-chunk staged in LDS per iteration
#define KSPLIT 16      // k-dimension split across blocks
#define KB (M / KSPLIT) // 64 k's per block

__global__ __launch_bounds__(256)
void diagq_kernel(const float* __restrict__ A1, const float* __restrict__ C1,
                  const float* __restrict__ A2, const float* __restrict__ C2,
                  const float* __restrict__ C3, const float* __restrict__ p1,
                  float* __restrict__ D /* [3][2][M] */)
{
    __shared__ float As_re[TI][KCH + 1];   // +1 pad -> stride 17, conflict-free reads
    __shared__ float As_im[TI][KCH + 1];
    __shared__ float Cs_re[KCH][TI];
    __shared__ float Cs_im[KCH][TI];
    __shared__ float red_re[256];
    __shared__ float red_im[256];

    const int t  = threadIdx.x;
    const int i0 = blockIdx.x * TI;
    const int q  = blockIdx.y;       // 0: A1*C1', 1: A2*C2', 2: A2*C3'  (Q3 uses A2 per reference!)
    const int k0 = blockIdx.z * KB;

    const float* __restrict__ A = (q == 0) ? A1 : A2;
    const float* __restrict__ C = (q == 0) ? C1 : ((q == 1) ? C2 : C3);

    const int i_local = t & 63;
    const int kslice  = t >> 6;      // 0..3

    // loader index precompute
    const int a_ii = t >> 2;               // 0..63 rows of A tile
    const int a_kk = (t & 3) << 2;         // float4 offset in k
    const int c_kk = t >> 4;               // 0..15 rows of C tile
    const int c_ii = (t & 15) << 2;        // float4 offset in i

    const size_t MM = (size_t)M * M;

    float acc_re = 0.f, acc_im = 0.f;

    for (int s = 0; s < KB / KCH; ++s) {
        const int kbase = k0 + s * KCH;

        // --- stage A tile: A[i0+ii, kbase+kk], coalesced along k ---
        {
            const size_t row = (size_t)(i0 + a_ii) * M + kbase + a_kk;
            const float4 are = *(const float4*)(A + row);
            const float4 aim = *(const float4*)(A + MM + row);
            As_re[a_ii][a_kk + 0] = are.x;
            As_re[a_ii][a_kk + 1] = are.y;
            As_re[a_ii][a_kk + 2] = are.z;
            As_re[a_ii][a_kk + 3] = are.w;
            As_im[a_ii][a_kk + 0] = aim.x;
            As_im[a_ii][a_kk + 1] = aim.y;
            As_im[a_ii][a_kk + 2] = aim.z;
            As_im[a_ii][a_kk + 3] = aim.w;
        }
        // --- stage C tile with fused p[k] complex scale: (p ⊙ C)[kbase+kk, i0+ii] ---
        {
            const int k = kbase + c_kk;
            const float pre = p1[k];
            const float pim = p1[M + k];
            const size_t row = (size_t)k * M + i0 + c_ii;
            const float4 cre = *(const float4*)(C + row);
            const float4 cim = *(const float4*)(C + MM + row);
            Cs_re[c_kk][c_ii + 0] = pre * cre.x - pim * cim.x;
            Cs_re[c_kk][c_ii + 1] = pre * cre.y - pim * cim.y;
            Cs_re[c_kk][c_ii + 2] = pre * cre.z - pim * cim.z;
            Cs_re[c_kk][c_ii + 3] = pre * cre.w - pim * cim.w;
            Cs_im[c_kk][c_ii + 0] = pre * cim.x + pim * cre.x;
            Cs_im[c_kk][c_ii + 1] = pre * cim.y + pim * cre.y;
            Cs_im[c_kk][c_ii + 2] = pre * cim.z + pim * cre.z;
            Cs_im[c_kk][c_ii + 3] = pre * cim.w + pim * cre.w;
        }
        __syncthreads();

        #pragma unroll
        for (int j = 0; j < 4; ++j) {
            const int kk = (kslice << 2) + j;
            const float a_re = As_re[i_local][kk];
            const float a_im = As_im[i_local][kk];
            const float c_re = Cs_re[kk][i_local];
            const float c_im = Cs_im[kk][i_local];
            acc_re += a_re * c_re - a_im * c_im;
            acc_im += a_re * c_im + a_im * c_re;
        }
        __syncthreads();
    }

    // reduce 4 k-slices per i, then one atomic per (i, comp)
    red_re[t] = acc_re;
    red_im[t] = acc_im;
    __syncthreads();
    if (t < 64) {
        const float sr = red_re[t] + red_re[t + 64] + red_re[t + 128] + red_re[t + 192];
        const float si = red_im[t] + red_im[t + 64] + red_im[t + 128] + red_im[t + 192];
        atomicAdd(&D[(q * 2 + 0) * M + i0 + t], sr);
        atomicAdd(&D[(q * 2 + 1) * M + i0 + t], si);
    }
}

__global__ __launch_bounds__(256)
void finalize_kernel(const float* __restrict__ Theta,
                     const float* __restrict__ A1, const float* __restrict__ B1, const float* __restrict__ C1,
                     const float* __restrict__ A2, const float* __restrict__ B2, const float* __restrict__ C2,
                     const float* __restrict__ A3, const float* __restrict__ B3, const float* __restrict__ C3,
                     const float* __restrict__ alpha, const float* __restrict__ belta,
                     const float* __restrict__ p2, const float* __restrict__ D,
                     float* __restrict__ out)
{
    const int i = blockIdx.x * blockDim.x + threadIdx.x;
    if (i >= M) return;
    const size_t MM = (size_t)M * M;
    const size_t dg = (size_t)i * M + i;

    const float th_re = Theta[dg], th_im = Theta[MM + dg];
    const float al = alpha[0], be = belta[0];

    float b_re = p2[i], b_im = p2[M + i];

    {   // b1 = alpha * dA1 ⊙c (Thd ⊙c dC1) - diagQ1 + dB1
        const float a_re = A1[dg], a_im = A1[MM + dg];
        const float c_re = C1[dg], c_im = C1[MM + dg];
        const float t_re = th_re * c_re - th_im * c_im;
        const float t_im = th_re * c_im + th_im * c_re;
        const float u_re = a_re * t_re - a_im * t_im;
        const float u_im = a_re * t_im + a_im * t_re;
        b_re += al * u_re - D[0 * M + i] + B1[dg];
        b_im += al * u_im - D[1 * M + i] + B1[MM + dg];
    }
    {   // b2
        const float a_re = A2[dg], a_im = A2[MM + dg];
        const float c_re = C2[dg], c_im = C2[MM + dg];
        const float t_re = th_re * c_re - th_im * c_im;
        const float t_im = th_re * c_im + th_im * c_re;
        const float u_re = a_re * t_re - a_im * t_im;
        const float u_im = a_re * t_im + a_im * t_re;
        b_re += be * u_re - D[2 * M + i] + B2[dg];
        b_im += be * u_im - D[3 * M + i] + B2[MM + dg];
    }
    {   // b3 (diag uses A3/C3/B3, but Q3 already used A2 per reference)
        const float a_re = A3[dg], a_im = A3[MM + dg];
        const float c_re = C3[dg], c_im = C3[MM + dg];
        const float t_re = th_re * c_re - th_im * c_im;
        const float t_im = th_re * c_im + th_im * c_re;
        const float u_re = a_re * t_re - a_im * t_im;
        const float u_im = a_re * t_im + a_im * t_re;
        b_re += be * u_re - D[4 * M + i] + B3[dg];
        b_im += be * u_im - D[5 * M + i] + B3[MM + dg];
    }

    const float inv = 1.0f / sqrtf(b_re * b_re + b_im * b_im);
    out[dg]      = b_re * inv;
    out[MM + dg] = b_im * inv;
}

extern "C" void kernel_launch(void* const* d_in, const int* in_sizes, int n_in,
                              void* d_out, int out_size, void* d_ws, size_t ws_size,
                              hipStream_t stream) {
    const float* Theta = (const float*)d_in[0];
    const float* A1    = (const float*)d_in[1];
    const float* B1    = (const float*)d_in[2];
    const float* C1    = (const float*)d_in[3];
    const float* A2    = (const float*)d_in[4];
    const float* B2    = (const float*)d_in[5];
    const float* C2    = (const float*)d_in[6];
    const float* A3    = (const float*)d_in[7];
    const float* B3    = (const float*)d_in[8];
    const float* C3    = (const float*)d_in[9];
    const float* alpha = (const float*)d_in[10];
    const float* belta = (const float*)d_in[11];
    const float* p1    = (const float*)d_in[12];
    const float* p2    = (const float*)d_in[13];
    float* out = (float*)d_out;
    float* D   = (float*)d_ws;   // 6*M floats of scratch accumulators

    // output is all-zero except the diagonal; d_out/d_ws are re-poisoned each call
    hipMemsetAsync(d_out, 0, (size_t)out_size * sizeof(float), stream);
    hipMemsetAsync(d_ws, 0, 6 * M * sizeof(float), stream);

    dim3 grid(M / TI, 3, KSPLIT);   // 16 x 3 x 16 = 768 blocks
    diagq_kernel<<<grid, 256, 0, stream>>>(A1, C1, A2, C2, C3, p1, D);

    finalize_kernel<<<dim3(M / 256), 256, 0, stream>>>(
        Theta, A1, B1, C1, A2, B2, C2, A3, B3, C3, alpha, belta, p2, D, out);
}

// Round 2
// 130.540 us; speedup vs baseline: 1.0418x; 1.0418x over previous
//
#include <hip/hip_runtime.h>
#include <math.h>

#define M 1024

// diag(Q) tiling: block = (32 i's) x (64 k's), staged in two 32x32 chunks
#define TI 32
#define KCH 32
#define KSPLIT 16
#define KB (M / KSPLIT)   // 64

__global__ __launch_bounds__(256)
void diagq_kernel(const float* __restrict__ A1, const float* __restrict__ C1,
                  const float* __restrict__ A2, const float* __restrict__ C2,
                  const float* __restrict__ C3, const float* __restrict__ p1,
                  float* __restrict__ D /* [3][2][KSPLIT][M] partials, fully written */)
{
    __shared__ float As_re[TI][KCH + 1];   // +1 pad: reads hit distinct banks
    __shared__ float As_im[TI][KCH + 1];
    __shared__ float Cs_re[KCH][TI];
    __shared__ float Cs_im[KCH][TI];
    __shared__ float red_re[256];
    __shared__ float red_im[256];

    const int t  = threadIdx.x;
    const int i0 = blockIdx.x * TI;
    const int q  = blockIdx.y;        // 0: A1*(p.C1), 1: A2*(p.C2), 2: A2*(p.C3) (ref uses A2!)
    const int z  = blockIdx.z;
    const int k0 = z * KB;

    const float* __restrict__ A = (q == 0) ? A1 : A2;
    const float* __restrict__ C = (q == 0) ? C1 : ((q == 1) ? C2 : C3);

    const size_t MM = (size_t)M * M;

    // loader mapping: 8 threads per row, float4 each -> 128B contiguous per 8 lanes
    const int l_row = t >> 3;          // 0..31
    const int l_c4  = (t & 7) << 2;    // 0,4,...,28

    // compute mapping
    const int i_local = t & 31;
    const int kslice  = t >> 5;        // 0..7, each covers 4 k's

    float acc_re = 0.f, acc_im = 0.f;

    #pragma unroll
    for (int s = 0; s < KB / KCH; ++s) {
        const int kbase = k0 + s * KCH;

        // --- A tile: A[i0+row, kbase+col], coalesced along k (one pass) ---
        {
            const size_t off = (size_t)(i0 + l_row) * M + kbase + l_c4;
            const float4 are = *(const float4*)(A + off);
            const float4 aim = *(const float4*)(A + MM + off);
            As_re[l_row][l_c4 + 0] = are.x; As_re[l_row][l_c4 + 1] = are.y;
            As_re[l_row][l_c4 + 2] = are.z; As_re[l_row][l_c4 + 3] = are.w;
            As_im[l_row][l_c4 + 0] = aim.x; As_im[l_row][l_c4 + 1] = aim.y;
            As_im[l_row][l_c4 + 2] = aim.z; As_im[l_row][l_c4 + 3] = aim.w;
        }
        // --- C tile with fused p[k] complex scale (one pass) ---
        {
            const int k = kbase + l_row;
            const float pre = p1[k];
            const float pim = p1[M + k];
            const size_t off = (size_t)k * M + i0 + l_c4;
            const float4 cre = *(const float4*)(C + off);
            const float4 cim = *(const float4*)(C + MM + off);
            Cs_re[l_row][l_c4 + 0] = pre * cre.x - pim * cim.x;
            Cs_re[l_row][l_c4 + 1] = pre * cre.y - pim * cim.y;
            Cs_re[l_row][l_c4 + 2] = pre * cre.z - pim * cim.z;
            Cs_re[l_row][l_c4 + 3] = pre * cre.w - pim * cim.w;
            Cs_im[l_row][l_c4 + 0] = pre * cim.x + pim * cre.x;
            Cs_im[l_row][l_c4 + 1] = pre * cim.y + pim * cre.y;
            Cs_im[l_row][l_c4 + 2] = pre * cim.z + pim * cre.z;
            Cs_im[l_row][l_c4 + 3] = pre * cim.w + pim * cre.w;
        }
        __syncthreads();

        #pragma unroll
        for (int j = 0; j < 4; ++j) {
            const int kk = (kslice << 2) + j;
            const float a_re = As_re[i_local][kk];
            const float a_im = As_im[i_local][kk];
            const float c_re = Cs_re[kk][i_local];
            const float c_im = Cs_im[kk][i_local];
            acc_re += a_re * c_re - a_im * c_im;
            acc_im += a_re * c_im + a_im * c_re;
        }
        __syncthreads();
    }

    // reduce 8 k-slices per i; write disjoint partial slot (no atomics, no zero-init)
    red_re[t] = acc_re;
    red_im[t] = acc_im;
    __syncthreads();
    if (t < TI) {
        float sr = 0.f, si = 0.f;
        #pragma unroll
        for (int s = 0; s < 8; ++s) { sr += red_re[t + 32 * s]; si += red_im[t + 32 * s]; }
        D[((size_t)(q * 2 + 0) * KSPLIT + z) * M + i0 + t] = sr;
        D[((size_t)(q * 2 + 1) * KSPLIT + z) * M + i0 + t] = si;
    }
}

// block i owns output row i of both planes: zero-fill + diagonal value
__global__ __launch_bounds__(256)
void finalize_kernel(const float* __restrict__ Theta,
                     const float* __restrict__ A1, const float* __restrict__ B1, const float* __restrict__ C1,
                     const float* __restrict__ A2, const float* __restrict__ B2, const float* __restrict__ C2,
                     const float* __restrict__ A3, const float* __restrict__ B3, const float* __restrict__ C3,
                     const float* __restrict__ alpha, const float* __restrict__ belta,
                     const float* __restrict__ p2, const float* __restrict__ D,
                     float* __restrict__ out)
{
    __shared__ float sv[128];

    const int t = threadIdx.x;
    const int i = blockIdx.x;
    const size_t MM = (size_t)M * M;
    const size_t dg = (size_t)i * M + i;

    // parallel gather: 96 D-partials + 20 diagonal scalars + p2/alpha/belta
    if (t < 96) {
        sv[t] = D[(size_t)t * M + i];               // D[qc][s][i], qc=t>>4, s=t&15
    } else if (t < 116) {
        const int j = t - 96;                        // 2*mat + comp
        const float* ptrs[10] = {Theta, A1, B1, C1, A2, B2, C2, A3, B3, C3};
        const float* P = ptrs[j >> 1];
        sv[t] = P[(j & 1) ? (MM + dg) : dg];
    } else if (t == 116) { sv[116] = p2[i]; }
    else if (t == 117)   { sv[117] = p2[M + i]; }
    else if (t == 118)   { sv[118] = alpha[0]; }
    else if (t == 119)   { sv[119] = belta[0]; }

    // zero-fill row i of both planes (one float4 per thread per plane)
    const float4 z4 = make_float4(0.f, 0.f, 0.f, 0.f);
    ((float4*)(out + (size_t)i * M))[t]      = z4;
    ((float4*)(out + MM + (size_t)i * M))[t] = z4;

    __syncthreads();

    if (t == 0) {
        float qs[6];
        #pragma unroll
        for (int qc = 0; qc < 6; ++qc) {
            float s = 0.f;
            #pragma unroll
            for (int k = 0; k < 16; ++k) s += sv[qc * 16 + k];
            qs[qc] = s;
        }
        const float th_re = sv[96], th_im = sv[97];
        const float al = sv[118], be = sv[119];

        float b_re = sv[116], b_im = sv[117];   // param2

        // b1: alpha * dA1 *c (Th *c dC1) - diagQ1 + dB1
        {
            const float a_re = sv[98],  a_im = sv[99];
            const float c_re = sv[102], c_im = sv[103];
            const float t_re = th_re * c_re - th_im * c_im;
            const float t_im = th_re * c_im + th_im * c_re;
            b_re += al * (a_re * t_re - a_im * t_im) - qs[0] + sv[100];
            b_im += al * (a_re * t_im + a_im * t_re) - qs[1] + sv[101];
        }
        // b2
        {
            const float a_re = sv[104], a_im = sv[105];
            const float c_re = sv[108], c_im = sv[109];
            const float t_re = th_re * c_re - th_im * c_im;
            const float t_im = th_re * c_im + th_im * c_re;
            b_re += be * (a_re * t_re - a_im * t_im) - qs[2] + sv[106];
            b_im += be * (a_re * t_im + a_im * t_re) - qs[3] + sv[107];
        }
        // b3 (diag part uses A3/C3/B3; Q3 used A2 upstream, per reference)
        {
            const float a_re = sv[110], a_im = sv[111];
            const float c_re = sv[114], c_im = sv[115];
            const float t_re = th_re * c_re - th_im * c_im;
            const float t_im = th_re * c_im + th_im * c_re;
            b_re += be * (a_re * t_re - a_im * t_im) - qs[4] + sv[112];
            b_im += be * (a_re * t_im + a_im * t_re) - qs[5] + sv[113];
        }

        const float inv = 1.0f / sqrtf(b_re * b_re + b_im * b_im);
        out[dg]      = b_re * inv;
        out[MM + dg] = b_im * inv;
    }
}

extern "C" void kernel_launch(void* const* d_in, const int* in_sizes, int n_in,
                              void* d_out, int out_size, void* d_ws, size_t ws_size,
                              hipStream_t stream) {
    const float* Theta = (const float*)d_in[0];
    const float* A1    = (const float*)d_in[1];
    const float* B1    = (const float*)d_in[2];
    const float* C1    = (const float*)d_in[3];
    const float* A2    = (const float*)d_in[4];
    const float* B2    = (const float*)d_in[5];
    const float* C2    = (const float*)d_in[6];
    const float* A3    = (const float*)d_in[7];
    const float* B3    = (const float*)d_in[8];
    const float* C3    = (const float*)d_in[9];
    const float* alpha = (const float*)d_in[10];
    const float* belta = (const float*)d_in[11];
    const float* p1    = (const float*)d_in[12];
    const float* p2    = (const float*)d_in[13];
    float* out = (float*)d_out;
    float* D   = (float*)d_ws;   // [3][2][16][1024] floats, fully written by diagq

    dim3 grid(M / TI, 3, KSPLIT);   // 32 x 3 x 16 = 1536 blocks
    diagq_kernel<<<grid, 256, 0, stream>>>(A1, C1, A2, C2, C3, p1, D);

    finalize_kernel<<<dim3(M), 256, 0, stream>>>(
        Theta, A1, B1, C1, A2, B2, C2, A3, B3, C3, alpha, belta, p2, D, out);
}

// Round 3
// 129.384 us; speedup vs baseline: 1.0511x; 1.0089x over previous
//
#include <hip/hip_runtime.h>
#include <math.h>

#define M 1024

#define TI 32
#define KCH 32
#define KSPLIT 16
#define KB (M / KSPLIT)   // 64 k's per block

// grid (32, 2, 16). qset 0: Q1 = A1*(p.C1). qset 1: Q2 = A2*(p.C2) AND Q3 = A2*(p.C3)
// (reference uses A2 for Q3!). A2 tile is loaded ONCE for both products.
// Also zero-fills the 8 MB output (spread across all 1024 blocks).
__global__ __launch_bounds__(256)
void diagq_kernel(const float* __restrict__ A1, const float* __restrict__ C1,
                  const float* __restrict__ A2, const float* __restrict__ C2,
                  const float* __restrict__ C3, const float* __restrict__ p1,
                  float* __restrict__ D /* [6][KSPLIT][M] */,
                  float* __restrict__ out /* zero-filled here */)
{
    __shared__ float As_re[TI][KCH + 1];
    __shared__ float As_im[TI][KCH + 1];
    __shared__ float Cb_re[KCH][TI + 1];   // +1 pad: kills 8-way write conflict
    __shared__ float Cb_im[KCH][TI + 1];
    __shared__ float Cc_re[KCH][TI + 1];
    __shared__ float Cc_im[KCH][TI + 1];
    __shared__ float red[4][256];

    const int t    = threadIdx.x;
    const int i0   = blockIdx.x * TI;
    const int qset = blockIdx.y;           // 0: A1/C1 ; 1: A2/{C2,C3}
    const int z    = blockIdx.z;
    const int k0   = z * KB;

    // ---- zero-fill our 8 KB slice of out (poisoned 0xAA each call) ----
    {
        const int bid = blockIdx.x + 32 * (blockIdx.y + 2 * blockIdx.z);  // 0..1023
        float4* o4 = (float4*)out + (size_t)bid * 512 + t;
        const float4 z4 = make_float4(0.f, 0.f, 0.f, 0.f);
        o4[0]   = z4;
        o4[256] = z4;
    }

    const float* __restrict__ A  = qset ? A2 : A1;
    const float* __restrict__ Cb = qset ? C2 : C1;

    const size_t MM = (size_t)M * M;

    // loader mapping: 8 threads/row, float4 each -> 128 B contiguous per 8 lanes
    const int l_row = t >> 3;          // 0..31
    const int l_c4  = (t & 7) << 2;    // 0,4,...,28

    // compute mapping
    const int i_local = t & 31;
    const int kslice  = t >> 5;        // 0..7, each covers 4 k's

    float b_re = 0.f, b_im = 0.f;      // acc for A*Cb
    float c_re_acc = 0.f, c_im_acc = 0.f;  // acc for A*Cc (qset==1 only)

    #pragma unroll
    for (int s = 0; s < KB / KCH; ++s) {
        const int kbase = k0 + s * KCH;

        // A tile: A[i0+row, kbase+col], coalesced along k
        {
            const size_t off = (size_t)(i0 + l_row) * M + kbase + l_c4;
            const float4 are = *(const float4*)(A + off);
            const float4 aim = *(const float4*)(A + MM + off);
            As_re[l_row][l_c4 + 0] = are.x; As_re[l_row][l_c4 + 1] = are.y;
            As_re[l_row][l_c4 + 2] = are.z; As_re[l_row][l_c4 + 3] = are.w;
            As_im[l_row][l_c4 + 0] = aim.x; As_im[l_row][l_c4 + 1] = aim.y;
            As_im[l_row][l_c4 + 2] = aim.z; As_im[l_row][l_c4 + 3] = aim.w;
        }
        // Cb tile with fused p[k] complex scale
        const int k = kbase + l_row;
        const float pre = p1[k];
        const float pim = p1[M + k];
        {
            const size_t off = (size_t)k * M + i0 + l_c4;
            const float4 cre = *(const float4*)(Cb + off);
            const float4 cim = *(const float4*)(Cb + MM + off);
            Cb_re[l_row][l_c4 + 0] = pre * cre.x - pim * cim.x;
            Cb_re[l_row][l_c4 + 1] = pre * cre.y - pim * cim.y;
            Cb_re[l_row][l_c4 + 2] = pre * cre.z - pim * cim.z;
            Cb_re[l_row][l_c4 + 3] = pre * cre.w - pim * cim.w;
            Cb_im[l_row][l_c4 + 0] = pre * cim.x + pim * cre.x;
            Cb_im[l_row][l_c4 + 1] = pre * cim.y + pim * cre.y;
            Cb_im[l_row][l_c4 + 2] = pre * cim.z + pim * cre.z;
            Cb_im[l_row][l_c4 + 3] = pre * cim.w + pim * cre.w;
        }
        if (qset) {   // Cc = C3 tile, same k's, same p scale
            const size_t off = (size_t)k * M + i0 + l_c4;
            const float4 cre = *(const float4*)(C3 + off);
            const float4 cim = *(const float4*)(C3 + MM + off);
            Cc_re[l_row][l_c4 + 0] = pre * cre.x - pim * cim.x;
            Cc_re[l_row][l_c4 + 1] = pre * cre.y - pim * cim.y;
            Cc_re[l_row][l_c4 + 2] = pre * cre.z - pim * cim.z;
            Cc_re[l_row][l_c4 + 3] = pre * cre.w - pim * cim.w;
            Cc_im[l_row][l_c4 + 0] = pre * cim.x + pim * cre.x;
            Cc_im[l_row][l_c4 + 1] = pre * cim.y + pim * cre.y;
            Cc_im[l_row][l_c4 + 2] = pre * cim.z + pim * cre.z;
            Cc_im[l_row][l_c4 + 3] = pre * cim.w + pim * cre.w;
        }
        __syncthreads();

        #pragma unroll
        for (int j = 0; j < 4; ++j) {
            const int kk = (kslice << 2) + j;
            const float a_re = As_re[i_local][kk];
            const float a_im = As_im[i_local][kk];
            {
                const float x_re = Cb_re[kk][i_local];
                const float x_im = Cb_im[kk][i_local];
                b_re += a_re * x_re - a_im * x_im;
                b_im += a_re * x_im + a_im * x_re;
            }
            if (qset) {
                const float x_re = Cc_re[kk][i_local];
                const float x_im = Cc_im[kk][i_local];
                c_re_acc += a_re * x_re - a_im * x_im;
                c_im_acc += a_re * x_im + a_im * x_re;
            }
        }
        __syncthreads();
    }

    red[0][t] = b_re;
    red[1][t] = b_im;
    red[2][t] = c_re_acc;
    red[3][t] = c_im_acc;
    __syncthreads();
    if (t < TI) {
        float s0 = 0.f, s1 = 0.f, s2 = 0.f, s3 = 0.f;
        #pragma unroll
        for (int s = 0; s < 8; ++s) {
            s0 += red[0][t + 32 * s];
            s1 += red[1][t + 32 * s];
            s2 += red[2][t + 32 * s];
            s3 += red[3][t + 32 * s];
        }
        if (qset == 0) {
            D[((size_t)(0 * KSPLIT) + z) * M + i0 + t] = s0;   // Q1 re
            D[((size_t)(1 * KSPLIT) + z) * M + i0 + t] = s1;   // Q1 im
        } else {
            D[((size_t)(2 * KSPLIT) + z) * M + i0 + t] = s0;   // Q2 re
            D[((size_t)(3 * KSPLIT) + z) * M + i0 + t] = s1;   // Q2 im
            D[((size_t)(4 * KSPLIT) + z) * M + i0 + t] = s2;   // Q3 re
            D[((size_t)(5 * KSPLIT) + z) * M + i0 + t] = s3;   // Q3 im
        }
    }
}

// one thread per diagonal index i; D reads fully coalesced across threads
__global__ __launch_bounds__(128)
void finalize_kernel(const float* __restrict__ Theta,
                     const float* __restrict__ A1, const float* __restrict__ B1, const float* __restrict__ C1,
                     const float* __restrict__ A2, const float* __restrict__ B2, const float* __restrict__ C2,
                     const float* __restrict__ A3, const float* __restrict__ B3, const float* __restrict__ C3,
                     const float* __restrict__ alpha, const float* __restrict__ belta,
                     const float* __restrict__ p2, const float* __restrict__ D,
                     float* __restrict__ out)
{
    const int i = blockIdx.x * 128 + threadIdx.x;
    const size_t MM = (size_t)M * M;
    const size_t dg = (size_t)i * M + i;

    float qs[6];
    #pragma unroll
    for (int qc = 0; qc < 6; ++qc) {
        float s = 0.f;
        #pragma unroll
        for (int z = 0; z < KSPLIT; ++z)
            s += D[((size_t)qc * KSPLIT + z) * M + i];
        qs[qc] = s;
    }

    const float th_re = Theta[dg], th_im = Theta[MM + dg];
    const float al = alpha[0], be = belta[0];

    float b_re = p2[i], b_im = p2[M + i];

    {   // b1 = alpha * dA1 *c (Th *c dC1) - diagQ1 + dB1
        const float a_re = A1[dg], a_im = A1[MM + dg];
        const float c_re = C1[dg], c_im = C1[MM + dg];
        const float t_re = th_re * c_re - th_im * c_im;
        const float t_im = th_re * c_im + th_im * c_re;
        b_re += al * (a_re * t_re - a_im * t_im) - qs[0] + B1[dg];
        b_im += al * (a_re * t_im + a_im * t_re) - qs[1] + B1[MM + dg];
    }
    {   // b2
        const float a_re = A2[dg], a_im = A2[MM + dg];
        const float c_re = C2[dg], c_im = C2[MM + dg];
        const float t_re = th_re * c_re - th_im * c_im;
        const float t_im = th_re * c_im + th_im * c_re;
        b_re += be * (a_re * t_re - a_im * t_im) - qs[2] + B2[dg];
        b_im += be * (a_re * t_im + a_im * t_re) - qs[3] + B2[MM + dg];
    }
    {   // b3 (diag uses A3/C3/B3; Q3 used A2 upstream per reference)
        const float a_re = A3[dg], a_im = A3[MM + dg];
        const float c_re = C3[dg], c_im = C3[MM + dg];
        const float t_re = th_re * c_re - th_im * c_im;
        const float t_im = th_re * c_im + th_im * c_re;
        b_re += be * (a_re * t_re - a_im * t_im) - qs[4] + B3[dg];
        b_im += be * (a_re * t_im + a_im * t_re) - qs[5] + B3[MM + dg];
    }

    const float inv = 1.0f / sqrtf(b_re * b_re + b_im * b_im);
    out[dg]      = b_re * inv;
    out[MM + dg] = b_im * inv;
}

extern "C" void kernel_launch(void* const* d_in, const int* in_sizes, int n_in,
                              void* d_out, int out_size, void* d_ws, size_t ws_size,
                              hipStream_t stream) {
    const float* Theta = (const float*)d_in[0];
    const float* A1    = (const float*)d_in[1];
    const float* B1    = (const float*)d_in[2];
    const float* C1    = (const float*)d_in[3];
    const float* A2    = (const float*)d_in[4];
    const float* B2    = (const float*)d_in[5];
    const float* C2    = (const float*)d_in[6];
    const float* A3    = (const float*)d_in[7];
    const float* B3    = (const float*)d_in[8];
    const float* C3    = (const float*)d_in[9];
    const float* alpha = (const float*)d_in[10];
    const float* belta = (const float*)d_in[11];
    const float* p1    = (const float*)d_in[12];
    const float* p2    = (const float*)d_in[13];
    float* out = (float*)d_out;
    float* D   = (float*)d_ws;   // [6][16][1024] floats, fully written by diagq

    dim3 grid(M / TI, 2, KSPLIT);   // 32 x 2 x 16 = 1024 blocks
    diagq_kernel<<<grid, 256, 0, stream>>>(A1, C1, A2, C2, C3, p1, D, out);

    finalize_kernel<<<dim3(M / 128), 128, 0, stream>>>(
        Theta, A1, B1, C1, A2, B2, C2, A3, B3, C3, alpha, belta, p2, D, out);
}